// Round 2
// baseline (89.818 us; speedup 1.0000x reference)
//
#include <hip/hip_runtime.h>

#define B     512
#define NBG   10000
#define F     32
#define H     128
#define NP    10240        // padded background count (multiple of 128)
#define NC    16
#define CHUNK 640          // NC*CHUNK == NP
#define WPB   8

// ---------------- Kernel A: fused MLP (blocks 0..511) + transpose/pad (blocks 512..591) ----------------
__global__ __launch_bounds__(128) void prep_kernel(
    const float* __restrict__ X,
    const float* __restrict__ xbg,
    const float* __restrict__ ybg,
    const float* __restrict__ W0, const float* __restrict__ b0,
    const float* __restrict__ W1, const float* __restrict__ b1,
    const float* __restrict__ Wout, const float* __restrict__ bout,
    float* __restrict__ babs,
    float* __restrict__ xbgT,
    float* __restrict__ ybgP)
{
    __shared__ float lds[128 * 33];
    const int t = threadIdx.x;

    if (blockIdx.x < B) {
        // ---- MLP for row b: babs[b][f] = |b_vec[b][f]| ----
        const int b = blockIdx.x;
        float* xrow = lds;          // 32
        float* h0   = lds + 32;     // 128
        float* h1   = lds + 160;    // 128

        if (t < F) xrow[t] = X[b * F + t];
        __syncthreads();

        float acc = b0[t];
        #pragma unroll
        for (int f = 0; f < F; ++f) acc += xrow[f] * W0[f * H + t];
        h0[t] = fmaxf(acc, 0.f);
        __syncthreads();

        acc = b1[t];
        #pragma unroll 8
        for (int j = 0; j < H; ++j) acc += h0[j] * W1[j * H + t];
        h1[t] = fmaxf(acc, 0.f);
        __syncthreads();

        if (t < F) {
            float a = bout[t];
            #pragma unroll 8
            for (int j = 0; j < H; ++j) a += h1[j] * Wout[j * F + t];
            babs[b * F + t] = fabsf(a);
        }
    } else {
        // ---- transpose 128 points into xbgT[f][n], pad tail with 1e30 ----
        const int nb = (blockIdx.x - B) * 128;

        #pragma unroll
        for (int k = 0; k < 32; ++k) {
            int idx = k * 128 + t;          // coalesced over global floats
            int nl  = idx >> 5;
            int f   = idx & 31;
            int n   = nb + nl;
            lds[nl * 33 + f] = (n < NBG) ? xbg[n * F + f] : 1e30f;
        }
        __syncthreads();

        #pragma unroll
        for (int f = 0; f < F; ++f)
            xbgT[f * NP + nb + t] = lds[t * 33 + f];   // coalesced 512B stores

        int n = nb + t;
        ybgP[nb + t] = (n < NBG) ? ybg[n] : 0.f;
    }
}

// ---------------- Kernel B: NW partial sums (coalesced feature-major reads) ----------------
// Block: 512 threads = 8 waves; wave w owns batch row b = blockIdx.x*8 + w.
// Lane l owns points p = n0 + 128*i + 2*l (+0,+1) -> float2 reads, 512B/wave/instr.
__global__ __launch_bounds__(512) void nw_partial(
    const float* __restrict__ X,
    const float* __restrict__ xbgT,
    const float* __restrict__ ybgP,
    const float* __restrict__ babs,
    float* __restrict__ psw,
    float* __restrict__ pswy)
{
    const int wid  = threadIdx.x >> 6;
    const int lane = threadIdx.x & 63;
    const int b    = blockIdx.x * WPB + wid;
    const int n0   = blockIdx.y * CHUNK;

    float xq[F], bv[F];
    const float4* xr = (const float4*)(X + b * F);
    const float4* br = (const float4*)(babs + b * F);
    #pragma unroll
    for (int q = 0; q < F / 4; ++q) {
        float4 xv = xr[q];
        float4 bb = br[q];
        xq[4*q+0] = xv.x; xq[4*q+1] = xv.y; xq[4*q+2] = xv.z; xq[4*q+3] = xv.w;
        bv[4*q+0] = bb.x; bv[4*q+1] = bb.y; bv[4*q+2] = bb.z; bv[4*q+3] = bb.w;
    }

    float sw = 0.f, swy = 0.f;

    #pragma unroll 1
    for (int i = 0; i < CHUNK / 128; ++i) {
        const int p = n0 + i * 128 + 2 * lane;
        float d0 = 0.f, d1 = 0.f;
        #pragma unroll
        for (int f = 0; f < F; ++f) {
            float2 v = *(const float2*)(xbgT + f * NP + p);
            d0 += bv[f] * fabsf(xq[f] - v.x);
            d1 += bv[f] * fabsf(xq[f] - v.y);
        }
        float2 y = *(const float2*)(ybgP + p);
        float w0 = __expf(-d0);
        float w1 = __expf(-d1);
        sw  += w0 + w1;
        swy += w0 * y.x + w1 * y.y;
    }

    #pragma unroll
    for (int off = 32; off > 0; off >>= 1) {
        sw  += __shfl_down(sw,  off);
        swy += __shfl_down(swy, off);
    }
    if (lane == 0) {
        psw [b * NC + blockIdx.y] = sw;
        pswy[b * NC + blockIdx.y] = swy;
    }
}

// ---------------- Kernel C: combine partials, normalize ----------------
__global__ __launch_bounds__(B) void nw_final(
    const float* __restrict__ psw,
    const float* __restrict__ pswy,
    float* __restrict__ out)
{
    const int b = threadIdx.x;
    float sw = 0.f, swy = 0.f;
    #pragma unroll
    for (int c = 0; c < NC; ++c) {
        sw  += psw [b * NC + c];
        swy += pswy[b * NC + c];
    }
    out[b] = swy / sw;
}

extern "C" void kernel_launch(void* const* d_in, const int* in_sizes, int n_in,
                              void* d_out, int out_size, void* d_ws, size_t ws_size,
                              hipStream_t stream)
{
    const float* X    = (const float*)d_in[0];
    const float* xbg  = (const float*)d_in[1];
    const float* ybg  = (const float*)d_in[2];
    const float* W0   = (const float*)d_in[3];
    const float* b0   = (const float*)d_in[4];
    const float* W1   = (const float*)d_in[5];
    const float* b1   = (const float*)d_in[6];
    const float* Wout = (const float*)d_in[7];
    const float* bout = (const float*)d_in[8];
    float* out = (float*)d_out;

    float* xbgT = (float*)d_ws;               // 32*10240 floats = 1.25 MiB
    float* ybgP = xbgT + F * NP;              // 10240 floats
    float* babs = ybgP + NP;                  // B*F
    float* psw  = babs + B * F;               // B*NC
    float* pswy = psw + B * NC;               // B*NC

    prep_kernel<<<B + NP / 128, H, 0, stream>>>(X, xbg, ybg, W0, b0, W1, b1,
                                                Wout, bout, babs, xbgT, ybgP);
    nw_partial<<<dim3(B / WPB, NC), 512, 0, stream>>>(X, xbgT, ybgP, babs, psw, pswy);
    nw_final<<<1, B, 0, stream>>>(psw, pswy, out);
}

// Round 3
// 46.486 us; speedup vs baseline: 1.9322x; 1.9322x over previous
//
#include <hip/hip_runtime.h>

#define B     512
#define NBG   10000
#define F     32
#define H     128
#define CHUNK 40
#define NBLK  250     // NBLK*CHUNK == NBG

// ---------------- Kernel A: per-row MLP -> transposed |b_vec| and X ----------------
// babsT[f][b] = |b_vec[b][f]|, XT[f][b] = X[b][f]
__global__ __launch_bounds__(128) void prep_kernel(
    const float* __restrict__ X,
    const float* __restrict__ W0, const float* __restrict__ b0,
    const float* __restrict__ W1, const float* __restrict__ b1,
    const float* __restrict__ Wout, const float* __restrict__ bout,
    float* __restrict__ XT,
    float* __restrict__ babsT)
{
    __shared__ float xrow[F];
    __shared__ float h0[H];
    __shared__ float h1[H];

    const int b = blockIdx.x;
    const int t = threadIdx.x;

    if (t < F) {
        float xv = X[b * F + t];
        xrow[t] = xv;
        XT[t * B + b] = xv;
    }
    __syncthreads();

    float acc = b0[t];
    #pragma unroll
    for (int f = 0; f < F; ++f) acc += xrow[f] * W0[f * H + t];
    h0[t] = fmaxf(acc, 0.f);
    __syncthreads();

    acc = b1[t];
    #pragma unroll 8
    for (int j = 0; j < H; ++j) acc += h0[j] * W1[j * H + t];
    h1[t] = fmaxf(acc, 0.f);
    __syncthreads();

    if (t < F) {
        float a = bout[t];
        #pragma unroll 8
        for (int j = 0; j < H; ++j) a += h1[j] * Wout[j * F + t];
        babsT[t * B + b] = fabsf(a);
    }
}

// ---------------- Kernel B: NW partial sums ----------------
// One thread per batch row b (512 threads = all of B). Grid.x = background chunk.
// Per-lane xq/bv pinned in VGPRs; background point features are wave-uniform ->
// scalar loads (SGPRs); inner op = v_sub(sgpr) + v_fma(abs) : 2 VALU per (f,n).
__global__ __launch_bounds__(512) void nw_partial(
    const float* __restrict__ XT,
    const float* __restrict__ babsT,
    const float* __restrict__ xbg,
    const float* __restrict__ ybg,
    float* __restrict__ psw,
    float* __restrict__ pswy)
{
    const int b  = threadIdx.x;
    const int n0 = blockIdx.x * CHUNK;

    float xq[F], bv[F];
    #pragma unroll
    for (int f = 0; f < F; ++f) {
        xq[f] = XT[f * B + b];       // coalesced: 64 lanes x 4B contiguous
        bv[f] = babsT[f * B + b];
        asm volatile("" : "+v"(xq[f]), "+v"(bv[f]));   // pin: forbid re-load
    }

    float sw = 0.f, swy = 0.f;

    #pragma unroll 2
    for (int n = n0; n < n0 + CHUNK; ++n) {
        const float* __restrict__ p = xbg + n * F;    // uniform -> s_load
        float d = 0.f;
        #pragma unroll
        for (int f = 0; f < F; ++f)
            d += bv[f] * fabsf(xq[f] - p[f]);
        const float w = __expf(-d);
        sw  += w;
        swy += w * ybg[n];
    }

    psw [blockIdx.x * B + b] = sw;    // coalesced
    pswy[blockIdx.x * B + b] = swy;
}

// ---------------- Kernel C: combine partials, normalize ----------------
__global__ __launch_bounds__(64) void nw_final(
    const float* __restrict__ psw,
    const float* __restrict__ pswy,
    float* __restrict__ out)
{
    const int b = blockIdx.x * 64 + threadIdx.x;
    float sw = 0.f, swy = 0.f;
    for (int c = 0; c < NBLK; ++c) {
        sw  += psw [c * B + b];       // coalesced across lanes
        swy += pswy[c * B + b];
    }
    out[b] = swy / sw;
}

extern "C" void kernel_launch(void* const* d_in, const int* in_sizes, int n_in,
                              void* d_out, int out_size, void* d_ws, size_t ws_size,
                              hipStream_t stream)
{
    const float* X    = (const float*)d_in[0];
    const float* xbg  = (const float*)d_in[1];
    const float* ybg  = (const float*)d_in[2];
    const float* W0   = (const float*)d_in[3];
    const float* b0   = (const float*)d_in[4];
    const float* W1   = (const float*)d_in[5];
    const float* b1   = (const float*)d_in[6];
    const float* Wout = (const float*)d_in[7];
    const float* bout = (const float*)d_in[8];
    float* out = (float*)d_out;

    float* XT    = (float*)d_ws;             // F*B floats
    float* babsT = XT + F * B;               // F*B floats
    float* psw   = babsT + F * B;            // NBLK*B floats
    float* pswy  = psw + NBLK * B;           // NBLK*B floats

    prep_kernel<<<B, H, 0, stream>>>(X, W0, b0, W1, b1, Wout, bout, XT, babsT);
    nw_partial<<<NBLK, B, 0, stream>>>(XT, babsT, xbg, ybg, psw, pswy);
    nw_final<<<B / 64, 64, 0, stream>>>(psw, pswy, out);
}